// Round 1
// baseline (266.509 us; speedup 1.0000x reference)
//
#include <hip/hip_runtime.h>

// Problem constants (fixed benchmark shapes)
#define SPX  512000            // D*H*W = 80*80*80
#define NBX  2                 // batch
#define NCH  32                // channels
#define NTOT (NBX*SPX)         // 1,024,000 voxels
#define NCL  28                // num classes
#define SEG  64                // labels per thread in scan passes
#define TTH  (NTOT/SEG)        // 16,000 threads (exact)
#define BS1  64
#define GR1  (TTH/BS1)         // 250 blocks
#define KCAP 256               // max supported max_triplet (actual k=200)
#define HS   29                // LDS histogram stride (odd -> spread banks)

__device__ __forceinline__ int faddr(int n, int c) {
  // f[n][c] with feats layout (B, C, D, H, W)
  int b = (n >= SPX) ? 1 : 0;
  int r = n - b * SPX;
  return (b * NCH + c) * SPX + r;   // max ~32.8M, fits int
}

// ---------------- Pass 1: per-thread label histograms ----------------
__global__ void k_hist(const int* __restrict__ lab, int* __restrict__ hist) {
  __shared__ int h[BS1 * HS];
  const int tid = threadIdx.x;
  const int t = blockIdx.x * BS1 + tid;
  for (int L = 0; L < NCL; ++L) h[tid * HS + L] = 0;
  const int4* p = (const int4*)(lab + t * SEG);
#pragma unroll
  for (int j = 0; j < SEG / 4; ++j) {
    int4 v = p[j];
    ++h[tid * HS + v.x];
    ++h[tid * HS + v.y];
    ++h[tid * HS + v.z];
    ++h[tid * HS + v.w];
  }
  for (int L = 0; L < NCL; ++L) hist[L * TTH + t] = h[tid * HS + L];
}

// ---------------- Pass 2: exclusive scan over threads, per label ----------------
__global__ void k_scan(int* __restrict__ hist, int* __restrict__ counts) {
  const int L = blockIdx.x;                 // 0..27
  int* a = hist + L * TTH;
  __shared__ int s[256];
  const int tid = threadIdx.x;
  const int CH = (TTH + 255) / 256;         // 63
  int lo = tid * CH; if (lo > TTH) lo = TTH;
  int hi = lo + CH;  if (hi > TTH) hi = TTH;
  int sum = 0;
  for (int i = lo; i < hi; ++i) sum += a[i];
  s[tid] = sum;
  __syncthreads();
  for (int off = 1; off < 256; off <<= 1) {
    int v = (tid >= off) ? s[tid - off] : 0;
    __syncthreads();
    s[tid] += v;
    __syncthreads();
  }
  if (tid == 255) counts[L] = s[255];       // total count of label L
  int run = s[tid] - sum;                   // exclusive prefix of my chunk
  for (int i = lo; i < hi; ++i) { int t0 = a[i]; a[i] = run; run += t0; }
}

// ---------------- Pass 3: ordered first-k selection + counter snapshots ----------------
__global__ void k_select(const int* __restrict__ lab, const int* __restrict__ P,
                         int* __restrict__ firstk, int* __restrict__ snap,
                         const int* __restrict__ kptr) {
  __shared__ int cur[BS1 * HS];
  const int tid = threadIdx.x;
  const int t = blockIdx.x * BS1 + tid;
  int k = kptr[0]; if (k > KCAP) k = KCAP;
  for (int L = 0; L < NCL; ++L) cur[tid * HS + L] = P[L * TTH + t];
  const int4* p = (const int4*)(lab + t * SEG);
  int n = t * SEG;
  for (int j = 0; j < SEG / 4; ++j) {
    int4 v = p[j];
#pragma unroll
    for (int q = 0; q < 4; ++q) {
      int L = (q == 0) ? v.x : (q == 1) ? v.y : (q == 2) ? v.z : v.w;
      int c = cur[tid * HS + L];
      if (L != 0 && c < k) {
        int slot = L * KCAP + c;
        firstk[slot] = n;
        int* srow = snap + slot * NCL;      // counters strictly BEFORE this voxel
        for (int L2 = 0; L2 < NCL; ++L2) srow[L2] = cur[tid * HS + L2];
      }
      cur[tid * HS + L] = c + 1;
      ++n;
    }
  }
}

// ---------------- Per-class: merge pos/neg lists via snapshot ranks, then triplets ----------------
__global__ void k_main(const float* __restrict__ feats, const float* __restrict__ dm,
                       const int* __restrict__ counts, const int* __restrict__ firstk,
                       const int* __restrict__ snap, const int* __restrict__ kptr,
                       float* __restrict__ perclass) {
  const int ii = blockIdx.x + 1;            // class 1..27
  const int tid = threadIdx.x;
  __shared__ int cnt_s[NCL];
  __shared__ unsigned int posmask_s, negmask_s;
  __shared__ int minsize_s, has_s, k_s;
  __shared__ int ipos[KCAP], ineg[KCAP];    // packed: idx | (label<<20)
  __shared__ float partial[8];

  if (tid < NCL) cnt_s[tid] = counts[tid];
  __syncthreads();

  if (tid == 0) {
    int k = kptr[0]; if (k > KCAP) k = KCAP; if (k < 0) k = 0;
    k_s = k;
    float ad[NCL];
    unsigned em = 0;
    float mind = 1e9f;
    for (int L = 0; L < NCL; ++L) {
      bool ex = (L != 0) && (cnt_s[L] > 0);
      float v = dm[ii * NCL + L];
      if (v == 0.0f) v = 256.0f;
      if (!ex) v = 1e9f;
      ad[L] = v;
      if (ex) em |= 1u << L;
      if (v < mind) mind = v;
    }
    unsigned pm = 0, nm = 0;
    int cp = 0, cn = 0;
    for (int L = 1; L < NCL; ++L) {
      if (((em >> L) & 1) && ad[L] == mind) { pm |= 1u << L; cp += cnt_s[L]; }
    }
    for (int L = 1; L < NCL; ++L) {
      if (L == ii) continue;
      if ((pm >> L) & 1) continue;
      nm |= 1u << L; cn += cnt_s[L];
    }
    int ca = cnt_s[ii];
    int ms = ca; if (cp < ms) ms = cp; if (cn < ms) ms = cn; if (k < ms) ms = k;
    posmask_s = pm; negmask_s = nm; minsize_s = ms;
    has_s = (((em >> ii) & 1) && ms > 0) ? 1 : 0;
  }
  __syncthreads();

  if (!has_s) {
    if (tid == 0) { perclass[2 * (ii - 1)] = 0.f; perclass[2 * (ii - 1) + 1] = 0.f; }
    return;                                  // uniform across block: safe
  }

  const int k = k_s;
  const unsigned pm = posmask_s, nm = negmask_s;

  // merge: each candidate computes its rank inside the pos/neg union from its snapshot
  for (int L = 1; L < NCL; ++L) {
    bool isp = (pm >> L) & 1, isn = (nm >> L) & 1;
    if (!isp && !isn) continue;
    int len = cnt_s[L]; if (len > k) len = k;
    for (int p = tid; p < len; p += 256) {
      const int slot = L * KCAP + p;
      const int x = firstk[slot];
      const int* srow = snap + slot * NCL;
      int pr = 0, nr = 0;
      for (int L2 = 1; L2 < NCL; ++L2) {
        int sv = srow[L2];
        if ((pm >> L2) & 1) pr += sv;
        if ((nm >> L2) & 1) nr += sv;
      }
      int packed = x | (L << 20);
      if (isp && pr < k) ipos[pr] = packed;
      if (isn && nr < k) ineg[nr] = packed;
    }
  }
  __syncthreads();

  // triplets: 8 groups of 32 lanes; lane = channel
  const int ms = minsize_s;
  const int grp = tid >> 5, lane = tid & 31;
  float acc = 0.f;
  for (int j = grp; j < ms; j += 8) {
    int na = firstk[ii * KCAP + j];
    int pp = ipos[j], nn = ineg[j];
    int np = pp & 0xFFFFF, lp = pp >> 20;
    int ng = nn & 0xFFFFF, ln = nn >> 20;
    float fa = feats[faddr(na, lane)];
    float fp = feats[faddr(np, lane)];
    float fn = feats[faddr(ng, lane)];
    float sp = fa * fp, sn = fa * fn;
#pragma unroll
    for (int o = 16; o >= 1; o >>= 1) {
      sp += __shfl_xor(sp, o, 64);
      sn += __shfl_xor(sn, o, 64);
    }
    if (lane == 0) {
      float dp = dm[ii * NCL + lp], dn = dm[ii * NCL + ln];
      float tl = sn - sp + 0.1f + (dn - dp) * 0.125f;
      if (tl > 0.f) acc += tl;
    }
  }
  if (lane == 0) partial[grp] = acc;
  __syncthreads();
  if (tid == 0) {
    float s = 0.f;
    for (int g = 0; g < 8; ++g) s += partial[g];
    perclass[2 * (ii - 1)] = s / (float)ms;
    perclass[2 * (ii - 1) + 1] = 1.f;
  }
}

// ---------------- finalize ----------------
__global__ void k_fin(const float* __restrict__ perclass, float* __restrict__ out) {
  if (threadIdx.x == 0 && blockIdx.x == 0) {
    float tot = 0.f, cc = 0.f;
    for (int i = 0; i < NCL - 1; ++i) { tot += perclass[2 * i]; cc += perclass[2 * i + 1]; }
    out[0] = (cc > 0.f) ? tot / cc : 0.f;
  }
}

extern "C" void kernel_launch(void* const* d_in, const int* in_sizes, int n_in,
                              void* d_out, int out_size, void* d_ws, size_t ws_size,
                              hipStream_t stream) {
  const float* feats = (const float*)d_in[0];
  const float* dm    = (const float*)d_in[1];
  const int*   lab   = (const int*)d_in[2];
  const int*   kptr  = (const int*)d_in[3];
  float* out = (float*)d_out;

  int* hist   = (int*)d_ws;                       // NCL*TTH ints
  int* counts = hist + NCL * TTH;                 // NCL ints
  int* firstk = counts + NCL;                     // NCL*KCAP ints
  int* snap   = firstk + NCL * KCAP;              // NCL*KCAP*NCL ints
  float* perclass = (float*)(snap + NCL * KCAP * NCL); // (NCL-1)*2 floats

  k_hist  <<<GR1, BS1, 0, stream>>>(lab, hist);
  k_scan  <<<NCL, 256, 0, stream>>>(hist, counts);
  k_select<<<GR1, BS1, 0, stream>>>(lab, hist, firstk, snap, kptr);
  k_main  <<<NCL - 1, 256, 0, stream>>>(feats, dm, counts, firstk, snap, kptr, perclass);
  k_fin   <<<1, 64, 0, stream>>>(perclass, out);
}